// Round 9
// baseline (1281.911 us; speedup 1.0000x reference)
//
#include <hip/hip_runtime.h>
#include <stdint.h>

#define VN   1000000
#define VDIM 256
#define GDIM 256
#define NH   16
#define NG   50000
#define HIDD 128
#define NTILES 15625   // VN / 64
#define TPB   5        // tiles per block; 15625 = 5 * 3125

using bf16x8 = __attribute__((ext_vector_type(8))) __bf16;
using f32x4  = __attribute__((ext_vector_type(4))) float;

__device__ __forceinline__ unsigned short f2bf(float f) {
  __bf16 h = (__bf16)f;
  return __builtin_bit_cast(unsigned short, h);
}
__device__ __forceinline__ bf16x8 pack8(float4 a, float4 b) {
  bf16x8 r;
  r[0] = (__bf16)a.x; r[1] = (__bf16)a.y; r[2] = (__bf16)a.z; r[3] = (__bf16)a.w;
  r[4] = (__bf16)b.x; r[5] = (__bf16)b.y; r[6] = (__bf16)b.z; r[7] = (__bf16)b.w;
  return r;
}
__device__ __forceinline__ f32x4 fzero4() { f32x4 z = {0.f, 0.f, 0.f, 0.f}; return z; }

// ---------------- weight prep: fp32 -> bf16 in MFMA B-fragment order ----------------
// For W[K][N]: frag element idx = ((c*(K/32)+s)*64 + lane)*8 + j  holds W[32s+8*(lane>>4)+j][16c+(lane&15)]
__global__ void k_prep(const float* __restrict__ s1, const float* __restrict__ s2,
                       const float* __restrict__ t1, const float* __restrict__ t2,
                       unsigned short* __restrict__ WB) {
  int t = blockIdx.x * 256 + threadIdx.x;
  const float* W; unsigned short* dst; int K, N, lid;
  if (t < 32768)       { W = s1; dst = WB;          K = 256; N = 128; lid = t; }
  else if (t < 65536)  { W = t1; dst = WB + 32768;  K = 256; N = 128; lid = t - 32768; }
  else if (t < 98304)  { W = t2; dst = WB + 65536;  K = 128; N = 256; lid = t - 65536; }
  else if (t < 100352) { W = s2; dst = WB + 98304;  K = 128; N = 16;  lid = t - 98304; }
  else return;
  int j = lid & 7, l = (lid >> 3) & 63, rem = lid >> 9;
  int KS = K >> 5;
  int s = rem % KS, c = rem / KS;
  int row = 32 * s + 8 * (l >> 4) + j;
  int col = 16 * c + (l & 15);
  dst[lid] = f2bf(W[row * N + col]);
}

// ---------------- zero: out [NG*GDIM] + denom [NG*NH] ----------------
__global__ void k_zero(float* __restrict__ out, float* __restrict__ denom) {
  int i = blockIdx.x * 256 + threadIdx.x;
  float4 z = make_float4(0.f, 0.f, 0.f, 0.f);
  if (i < NG * GDIM / 4) ((float4*)out)[i] = z;
  int j = i - NG * GDIM / 4;
  if (j >= 0 && j < NG * NH / 4) ((float4*)denom)[j] = z;
}

// ---------------- fused main: 512 thr, 2 blocks/CU, W1 in registers ----------------
// LDS (68 KB): Xs bf16[64][512B] swz [0,32768); Hs [32768,49152); Ts [49152,65536);
//              exs f32[64][16] [65536,69632)
// Per tile: A(8 float4 loads -> 4x 16B swz LDS writes) bar | B(MFMA, W1 regs) bar |
//           C1(scores, WS2 streamed) C2(layer2, W2 streamed per-ks) bar | D E.
// VGPR budget: W1 64 held + transient peaks ~122 <= 128 (launch_bounds 512,4 -> 2 blk/CU).
__global__ __launch_bounds__(512, 4) void k_main(
    const float* __restrict__ X,
    const unsigned short* __restrict__ WBs1,
    const unsigned short* __restrict__ WBt1,
    const unsigned short* __restrict__ WBs2,
    const unsigned short* __restrict__ WBt2,
    const int* __restrict__ seg,
    float* __restrict__ denom,
    float* __restrict__ out) {
  __shared__ __align__(16) char U[69632];
  char*  const Xs = U;
  char*  const Hs = U + 32768;
  char*  const Ts = U + 49152;
  float* const exs = (float*)(U + 65536);

  const int tid  = threadIdx.x;
  const int lane = tid & 63;
  const int w    = tid >> 6;       // 0..7
  const int lg   = lane >> 4;
  const int ml   = lane & 15;
  const int t0   = blockIdx.x * TPB;

  // ---- hoist layer-1 B-fragments: wave w<4 -> Sw1 cf {2w,2w+1}; w>=4 -> Tw1 (64 VGPR)
  const unsigned short* Wb1 = (w < 4) ? WBs1 : WBt1;
  const int cw = 2 * (w & 3);
  bf16x8 W1[2][8];
  #pragma unroll
  for (int ci = 0; ci < 2; ++ci)
    #pragma unroll
    for (int ks = 0; ks < 8; ++ks)
      W1[ci][ks] = *(const bf16x8*)(Wb1 + (size_t)(((cw + ci) * 8 + ks) * 64 + lane) * 8);

  // ---- preload seg ids for all TPB tiles
  int gvs[TPB];
  #pragma unroll
  for (int i = 0; i < TPB; ++i) gvs[i] = seg[(size_t)(t0 + i) * 64 + lane];

  #pragma unroll 1
  for (int it = 0; it < TPB; ++it) {
    const int t = t0 + it;
    const int gv = gvs[it];
    const int gp = __shfl_up(gv, 1, 64);
    const unsigned long long bmask = __ballot(gv != gp) | 1ull;

    // ---- Phase A: 8 float4 (pairwise) -> 4x 16B swizzled LDS writes (2-way, free)
    {
      const float4* Xg = (const float4*)(X + (size_t)t * 64 * VDIM);
      float4 xr[8];
      #pragma unroll
      for (int p = 0; p < 4; ++p) {
        xr[2 * p]     = Xg[2 * tid + 1024 * p];
        xr[2 * p + 1] = Xg[2 * tid + 1024 * p + 1];
      }
      #pragma unroll
      for (int p = 0; p < 4; ++p) {
        const int c32 = tid + 512 * p;          // 32B fp32 pair index
        const int row = c32 >> 5, c8 = c32 & 31;
        *(bf16x8*)(Xs + row * 512 + ((c8 * 16) ^ ((row & 7) << 4))) = pack8(xr[2 * p], xr[2 * p + 1]);
      }
    }
    __syncthreads();   // bar1: Xs ready (also: D(t-1) exs reads done before C1(t) rewrites)

    // ---- Phase B: C1[64][256] = relu(X @ [Sw1|Tw1]); W1 from registers
    {
      f32x4 acc[4][2];
      #pragma unroll
      for (int r = 0; r < 4; ++r) { acc[r][0] = fzero4(); acc[r][1] = fzero4(); }
      #pragma unroll
      for (int ks = 0; ks < 8; ++ks) {
        bf16x8 A[4];
        #pragma unroll
        for (int r = 0; r < 4; ++r) {
          const int row = 16 * r + ml;
          const int cbyte = 64 * ks + 16 * lg;
          A[r] = *(const bf16x8*)(Xs + row * 512 + (cbyte ^ ((row & 7) << 4)));
        }
        #pragma unroll
        for (int ci = 0; ci < 2; ++ci)
          #pragma unroll
          for (int r = 0; r < 4; ++r)
            acc[r][ci] = __builtin_amdgcn_mfma_f32_16x16x32_bf16(A[r], W1[ci][ks], acc[r][ci], 0, 0, 0);
      }
      // relu + bf16 -> Hs (waves 0-3) / Ts (waves 4-7), swizzled 256B rows
      char* const dst = (w < 4) ? Hs : Ts;
      #pragma unroll
      for (int ci = 0; ci < 2; ++ci) {
        const int colf = cw + ci;
        #pragma unroll
        for (int r = 0; r < 4; ++r)
          #pragma unroll
          for (int j = 0; j < 4; ++j) {
            const int row = 16 * r + 4 * lg + j;
            const int col = 16 * colf + ml;
            float v = acc[r][ci][j];
            v = v > 0.f ? v : 0.f;
            *(unsigned short*)(dst + row * 256 + ((col * 2) ^ ((row & 7) << 4))) = f2bf(v);
          }
      }
    }
    __syncthreads();   // bar2: Hs/Ts complete, Xs reads done

    // ---- Phase C1 (waves 0-3): scores rows 16w..16w+15; ex -> exs + denom atomics
    if (w < 4) {
      f32x4 sa = fzero4();
      #pragma unroll
      for (int ks = 0; ks < 4; ++ks) {
        const int row = 16 * w + ml;
        const int cb = 64 * ks + 16 * lg;
        bf16x8 A2 = *(const bf16x8*)(Hs + row * 256 + (cb ^ ((row & 7) << 4)));
        bf16x8 B2 = *(const bf16x8*)(WBs2 + (size_t)(ks * 64 + lane) * 8);   // L1-hot stream
        sa = __builtin_amdgcn_mfma_f32_16x16x32_bf16(A2, B2, sa, 0, 0, 0);
      }
      const int rowbase = 16 * w + 4 * lg;
      float ex[4]; int gs[4];
      #pragma unroll
      for (int j = 0; j < 4; ++j) {
        ex[j] = __expf(sa[j]);                     // |score| ~< 1.5: no max-subtract needed
        gs[j] = __shfl(gv, rowbase + j, 64);
        exs[(rowbase + j) * 16 + ml] = ex[j];
      }
      float accd = ex[0]; int gcur = gs[0];
      #pragma unroll
      for (int j = 1; j < 4; ++j) {
        if (gs[j] == gcur) accd += ex[j];
        else { atomicAdd(denom + (size_t)gcur * NH + ml, accd); gcur = gs[j]; accd = ex[j]; }
      }
      atomicAdd(denom + (size_t)gcur * NH + ml, accd);
    }

    // ---- Phase C2: R = T1 @ Tw2; wave w -> col-frags {2w,2w+1}; W2 streamed per-ks (L1/L2)
    f32x4 racc[4][2];
    #pragma unroll
    for (int r = 0; r < 4; ++r) { racc[r][0] = fzero4(); racc[r][1] = fzero4(); }
    #pragma unroll
    for (int ks = 0; ks < 4; ++ks) {
      bf16x8 A[4];
      #pragma unroll
      for (int r = 0; r < 4; ++r) {
        const int row = 16 * r + ml;
        const int cbyte = 64 * ks + 16 * lg;
        A[r] = *(const bf16x8*)(Ts + row * 256 + (cbyte ^ ((row & 7) << 4)));
      }
      #pragma unroll
      for (int ci = 0; ci < 2; ++ci) {
        bf16x8 B = *(const bf16x8*)(WBt2 + (size_t)(((2 * w + ci) * 4 + ks) * 64 + lane) * 8);
        #pragma unroll
        for (int r = 0; r < 4; ++r)
          racc[r][ci] = __builtin_amdgcn_mfma_f32_16x16x32_bf16(A[r], B, racc[r][ci], 0, 0, 0);
      }
    }
    __syncthreads();   // bar3: exs written by all C1 waves; Hs/Ts reads done

    // ---- Phase D: racc = relu(racc) * ex[row][2w+ci]  (exs read is a broadcast)
    #pragma unroll
    for (int r = 0; r < 4; ++r)
      #pragma unroll
      for (int j = 0; j < 4; ++j) {
        const int row = 16 * r + 4 * lg + j;
        const float2 e = *(const float2*)(exs + row * 16 + 2 * w);
        float v0 = racc[r][0][j]; v0 = v0 > 0.f ? v0 : 0.f; racc[r][0][j] = v0 * e.x;
        float v1 = racc[r][1][j]; v1 = v1 > 0.f ? v1 : 0.f; racc[r][1][j] = v1 * e.y;
      }

    // ---- Phase E: in-register segmented column sums; interior -> store, edge -> atomic
    unsigned long long mm = bmask;
    while (mm) {
      int a = __builtin_ctzll(mm);
      mm &= mm - 1;
      int b = mm ? __builtin_ctzll(mm) : 64;
      int g = __shfl(gv, a, 64);
      float s0 = 0.f, s1 = 0.f;
      #pragma unroll
      for (int r = 0; r < 4; ++r)
        #pragma unroll
        for (int j = 0; j < 4; ++j) {
          const int row = 16 * r + 4 * lg + j;
          const float msk = ((unsigned)(row - a) < (unsigned)(b - a)) ? 1.f : 0.f;
          s0 = fmaf(msk, racc[r][0][j], s0);
          s1 = fmaf(msk, racc[r][1][j], s1);
        }
      s0 += __shfl_xor(s0, 16, 64); s0 += __shfl_xor(s0, 32, 64);
      s1 += __shfl_xor(s1, 16, 64); s1 += __shfl_xor(s1, 32, 64);
      const bool edge = (a == 0) || (b == 64);
      if (lane < 16) {
        float* dst = out + (size_t)g * GDIM + 32 * w + lane;
        if (edge) { atomicAdd(dst, s0); atomicAdd(dst + 16, s1); }
        else      { dst[0] = s0; dst[16] = s1; }
      }
    }
  }
}

// ---------------- epilogue: out[g][c] /= denom[g][c/16]; empty graphs -> 0 ----------------
__global__ void k_div(float* __restrict__ out, const float* __restrict__ denom) {
  int i = blockIdx.x * 256 + threadIdx.x;
  if (i >= NG * GDIM / 4) return;
  float d = denom[(size_t)(i >> 6) * NH + ((i & 63) >> 2)];
  float r = d > 0.f ? 1.0f / d : 0.f;
  float4 v = ((float4*)out)[i];
  v.x *= r; v.y *= r; v.z *= r; v.w *= r;
  ((float4*)out)[i] = v;
}

extern "C" void kernel_launch(void* const* d_in, const int* in_sizes, int n_in,
                              void* d_out, int out_size, void* d_ws, size_t ws_size,
                              hipStream_t stream) {
  (void)in_sizes; (void)n_in; (void)out_size; (void)ws_size;
  const float* X  = (const float*)d_in[0];
  const int* seg  = (const int*)d_in[1];
  const float* s1 = (const float*)d_in[3];
  const float* s2 = (const float*)d_in[4];
  const float* t1 = (const float*)d_in[5];
  const float* t2 = (const float*)d_in[6];
  float* out = (float*)d_out;
  char* ws = (char*)d_ws;

  unsigned short* WB = (unsigned short*)ws;
  float* denom = (float*)(ws + (1 << 19));

  k_prep<<<392, 256, 0, stream>>>(s1, s2, t1, t2, WB);
  k_zero<<<13282, 256, 0, stream>>>(out, denom);
  k_main<<<NTILES / TPB, 512, 0, stream>>>(X, WB, WB + 32768, WB + 98304, WB + 65536,
                                           seg, denom, out);
  k_div<<<12500, 256, 0, stream>>>(out, denom);
}

// Round 10
// 607.126 us; speedup vs baseline: 2.1114x; 2.1114x over previous
//
#include <hip/hip_runtime.h>
#include <stdint.h>

#define VN   1000000
#define VDIM 256
#define GDIM 256
#define NH   16
#define NG   50000
#define HIDD 128
#define NBLK 7813      // ceil(VN / 128)

using bf16x8 = __attribute__((ext_vector_type(8))) __bf16;
using f32x4  = __attribute__((ext_vector_type(4))) float;

__device__ __forceinline__ unsigned short f2bf(float f) {
  __bf16 h = (__bf16)f;
  return __builtin_bit_cast(unsigned short, h);
}
__device__ __forceinline__ bf16x8 pack8(float4 a, float4 b) {
  bf16x8 r;
  r[0] = (__bf16)a.x; r[1] = (__bf16)a.y; r[2] = (__bf16)a.z; r[3] = (__bf16)a.w;
  r[4] = (__bf16)b.x; r[5] = (__bf16)b.y; r[6] = (__bf16)b.z; r[7] = (__bf16)b.w;
  return r;
}
__device__ __forceinline__ f32x4 fzero4() { f32x4 z = {0.f, 0.f, 0.f, 0.f}; return z; }

// ---------------- weight prep: fp32 -> bf16 in MFMA B-fragment order ----------------
// For W[K][N]: frag element idx = ((c*(K/32)+s)*64 + lane)*8 + j  holds W[32s+8*(lane>>4)+j][16c+(lane&15)]
__global__ void k_prep(const float* __restrict__ s1, const float* __restrict__ s2,
                       const float* __restrict__ t1, const float* __restrict__ t2,
                       unsigned short* __restrict__ WB) {
  int t = blockIdx.x * 256 + threadIdx.x;
  const float* W; unsigned short* dst; int K, N, lid;
  if (t < 32768)       { W = s1; dst = WB;          K = 256; N = 128; lid = t; }
  else if (t < 65536)  { W = t1; dst = WB + 32768;  K = 256; N = 128; lid = t - 32768; }
  else if (t < 98304)  { W = t2; dst = WB + 65536;  K = 128; N = 256; lid = t - 65536; }
  else if (t < 100352) { W = s2; dst = WB + 98304;  K = 128; N = 16;  lid = t - 98304; }
  else return;
  int j = lid & 7, l = (lid >> 3) & 63, rem = lid >> 9;
  int KS = K >> 5;
  int s = rem % KS, c = rem / KS;
  int row = 32 * s + 8 * (l >> 4) + j;
  int col = 16 * c + (l & 15);
  dst[lid] = f2bf(W[row * N + col]);
}

// ---------------- zero: out [NG*GDIM] + denom [NG*NH] ----------------
__global__ void k_zero(float* __restrict__ out, float* __restrict__ denom) {
  int i = blockIdx.x * 256 + threadIdx.x;
  float4 z = make_float4(0.f, 0.f, 0.f, 0.f);
  if (i < NG * GDIM / 4) ((float4*)out)[i] = z;
  int j = i - NG * GDIM / 4;
  if (j >= 0 && j < NG * NH / 4) ((float4*)denom)[j] = z;
}

// ---------------- fused main: one 128-row tile per block, 512 thr, 2 blocks/CU ----------------
// LDS (72 KB): Xs bf16[128][512B] swz [0,65536); after bar2 aliased by Hs[128][256B] [0,32768)
//              + Ts[128][256B] [32768,65536); exs f32[128][16] [65536,73728)
// 128-row tiles halve per-row weight-stream count, barriers and phase turnarounds vs 64-row.
// Nothing held in registers across barriers except MFMA acc (AGPRs). VGPR cap 128 (lb 512,2).
__global__ __launch_bounds__(512, 2) void k_main(
    const float* __restrict__ X,
    const unsigned short* __restrict__ WBs1,
    const unsigned short* __restrict__ WBt1,
    const unsigned short* __restrict__ WBs2,
    const unsigned short* __restrict__ WBt2,
    const int* __restrict__ seg,
    float* __restrict__ denom,
    float* __restrict__ out) {
  __shared__ __align__(16) char U[73728];
  char*  const Xs = U;
  char*  const Hs = U;             // aliases Xs after bar2
  char*  const Ts = U + 32768;
  float* const exs = (float*)(U + 65536);

  const int tid  = threadIdx.x;
  const int lane = tid & 63;
  const int w    = tid >> 6;       // 0..7
  const int lg   = lane >> 4;
  const int ml   = lane & 15;
  const size_t base = (size_t)blockIdx.x * 128;

  // per-lane graph ids for the tile's 128 rows (two 64-row halves); -1 = invalid (tail)
  const int gv0 = (base + lane < VN)      ? seg[base + lane]      : -1;
  const int gv1 = (base + 64 + lane < VN) ? seg[base + 64 + lane] : -1;

  // ---- Phase A: stage X tile -> bf16 LDS, 512B rows, swizzle byte^=((row&7)<<4)
  // two groups of 4 float4-pairs to bound the transient register window
  {
    const float4* Xg = (const float4*)(X + base * VDIM);
    #pragma unroll
    for (int q = 0; q < 2; ++q) {
      float4 xr[8];
      #pragma unroll
      for (int pp = 0; pp < 4; ++pp) {
        const int p = 4 * q + pp;
        const int c32 = tid + 512 * p;
        const int row = c32 >> 5;
        const bool ok = (base + row) < VN;
        xr[2 * pp]     = ok ? Xg[2 * c32]     : make_float4(0.f, 0.f, 0.f, 0.f);
        xr[2 * pp + 1] = ok ? Xg[2 * c32 + 1] : make_float4(0.f, 0.f, 0.f, 0.f);
      }
      #pragma unroll
      for (int pp = 0; pp < 4; ++pp) {
        const int p = 4 * q + pp;
        const int c32 = tid + 512 * p;
        const int row = c32 >> 5, c8 = c32 & 31;
        *(bf16x8*)(Xs + row * 512 + ((c8 * 16) ^ ((row & 7) << 4))) = pack8(xr[2 * pp], xr[2 * pp + 1]);
      }
    }
  }
  __syncthreads();   // bar1: Xs ready

  // ---- Phase B: C1[128][256] = relu(X @ [Sw1|Tw1]); waves 0-3 -> Sw1 cf{2w,2w+1}, 4-7 -> Tw1
  const unsigned short* Wb1 = (w < 4) ? WBs1 : WBt1;
  const int cw = 2 * (w & 3);
  {
    f32x4 acc[8][2];
    #pragma unroll
    for (int r = 0; r < 8; ++r) { acc[r][0] = fzero4(); acc[r][1] = fzero4(); }
    #pragma unroll
    for (int ks = 0; ks < 8; ++ks) {
      bf16x8 A[8];
      #pragma unroll
      for (int r = 0; r < 8; ++r) {
        const int row = 16 * r + ml;
        const int cbyte = 64 * ks + 16 * lg;
        A[r] = *(const bf16x8*)(Xs + row * 512 + (cbyte ^ ((row & 7) << 4)));
      }
      #pragma unroll
      for (int ci = 0; ci < 2; ++ci) {
        bf16x8 B = *(const bf16x8*)(Wb1 + (size_t)(((cw + ci) * 8 + ks) * 64 + lane) * 8);
        #pragma unroll
        for (int r = 0; r < 8; ++r)
          acc[r][ci] = __builtin_amdgcn_mfma_f32_16x16x32_bf16(A[r], B, acc[r][ci], 0, 0, 0);
      }
    }
    __syncthreads();   // bar2: all Xs reads done; U becomes Hs/Ts

    // relu + bf16 -> Hs (waves 0-3) / Ts (waves 4-7), [128][256B] swizzled rows
    char* const dst = (w < 4) ? Hs : Ts;
    #pragma unroll
    for (int ci = 0; ci < 2; ++ci) {
      const int colf = cw + ci;
      #pragma unroll
      for (int r = 0; r < 8; ++r)
        #pragma unroll
        for (int j = 0; j < 4; ++j) {
          const int row = 16 * r + 4 * lg + j;
          const int col = 16 * colf + ml;
          float v = acc[r][ci][j];
          v = v > 0.f ? v : 0.f;
          *(unsigned short*)(dst + row * 256 + ((col * 2) ^ ((row & 7) << 4))) = f2bf(v);
        }
    }
  }
  __syncthreads();   // bar3: Hs/Ts complete

  // ---- Phase C1: scores rows 16w..16w+15 (all 8 waves); ex -> exs + denom atomics
  {
    f32x4 sa = fzero4();
    #pragma unroll
    for (int ks = 0; ks < 4; ++ks) {
      const int row = 16 * w + ml;
      const int cb = 64 * ks + 16 * lg;
      bf16x8 A2 = *(const bf16x8*)(Hs + row * 256 + (cb ^ ((row & 7) << 4)));
      bf16x8 B2 = *(const bf16x8*)(WBs2 + (size_t)(ks * 64 + lane) * 8);
      sa = __builtin_amdgcn_mfma_f32_16x16x32_bf16(A2, B2, sa, 0, 0, 0);
    }
    const int rowbase = 16 * w + 4 * lg;
    const int gvh = (w < 4) ? gv0 : gv1;
    float ex[4]; int gs[4];
    #pragma unroll
    for (int j = 0; j < 4; ++j) {
      ex[j] = __expf(sa[j]);                     // |score| ~< 1.5: no max-subtract needed
      gs[j] = __shfl(gvh, (rowbase & 63) + j, 64);
      exs[(rowbase + j) * 16 + ml] = ex[j];
    }
    float accd = ex[0]; int gcur = gs[0];
    #pragma unroll
    for (int j = 1; j < 4; ++j) {
      if (gs[j] == gcur) accd += ex[j];
      else {
        if (gcur >= 0) atomicAdd(denom + (size_t)gcur * NH + ml, accd);
        gcur = gs[j]; accd = ex[j];
      }
    }
    if (gcur >= 0) atomicAdd(denom + (size_t)gcur * NH + ml, accd);
  }

  // ---- Phase C2: R = T1 @ Tw2; wave w -> col-frags {2w,2w+1} of 16
  f32x4 racc[8][2];
  #pragma unroll
  for (int r = 0; r < 8; ++r) { racc[r][0] = fzero4(); racc[r][1] = fzero4(); }
  #pragma unroll
  for (int ks = 0; ks < 4; ++ks) {
    bf16x8 A[8];
    #pragma unroll
    for (int r = 0; r < 8; ++r) {
      const int row = 16 * r + ml;
      const int cbyte = 64 * ks + 16 * lg;
      A[r] = *(const bf16x8*)(Ts + row * 256 + (cbyte ^ ((row & 7) << 4)));
    }
    #pragma unroll
    for (int ci = 0; ci < 2; ++ci) {
      bf16x8 B = *(const bf16x8*)(WBt2 + (size_t)(((2 * w + ci) * 4 + ks) * 64 + lane) * 8);
      #pragma unroll
      for (int r = 0; r < 8; ++r)
        racc[r][ci] = __builtin_amdgcn_mfma_f32_16x16x32_bf16(A[r], B, racc[r][ci], 0, 0, 0);
    }
  }
  __syncthreads();   // bar4: exs fully written

  // ---- Phase D: racc = relu(racc) * ex[row][2w+ci]
  #pragma unroll
  for (int r = 0; r < 8; ++r)
    #pragma unroll
    for (int j = 0; j < 4; ++j) {
      const int row = 16 * r + 4 * lg + j;
      const float2 e = *(const float2*)(exs + row * 16 + 2 * w);
      float v0 = racc[r][0][j]; v0 = v0 > 0.f ? v0 : 0.f; racc[r][0][j] = v0 * e.x;
      float v1 = racc[r][1][j]; v1 = v1 > 0.f ? v1 : 0.f; racc[r][1][j] = v1 * e.y;
    }

  // ---- Phase E: segmented column sums per 64-row half; rf-skip keeps it O(rows)
  #pragma unroll
  for (int h = 0; h < 2; ++h) {
    const int gvh = h ? gv1 : gv0;
    const int gph = __shfl_up(gvh, 1, 64);
    unsigned long long mm = __ballot(gvh != gph) | 1ull;
    while (mm) {
      const int a = __builtin_ctzll(mm);
      mm &= mm - 1;
      const int b = mm ? __builtin_ctzll(mm) : 64;
      const int g = __shfl(gvh, a, 64);
      if (g < 0) continue;
      float s0 = 0.f, s1 = 0.f;
      #pragma unroll
      for (int rr = 0; rr < 4; ++rr) {
        const int r = 4 * h + rr;
        const int lrb = 16 * rr;                 // local row base of this rf within the half
        if (lrb + 15 < a || lrb > b - 1) continue;   // wave-uniform rf skip
        #pragma unroll
        for (int j = 0; j < 4; ++j) {
          const int lrow = lrb + 4 * lg + j;
          const float msk = ((unsigned)(lrow - a) < (unsigned)(b - a)) ? 1.f : 0.f;
          s0 = fmaf(msk, racc[r][0][j], s0);
          s1 = fmaf(msk, racc[r][1][j], s1);
        }
      }
      s0 += __shfl_xor(s0, 16, 64); s0 += __shfl_xor(s0, 32, 64);
      s1 += __shfl_xor(s1, 16, 64); s1 += __shfl_xor(s1, 32, 64);
      const bool edge = (a == 0) || (b == 64);
      if (lane < 16) {
        float* dst = out + (size_t)g * GDIM + 32 * w + lane;
        if (edge) { atomicAdd(dst, s0); atomicAdd(dst + 16, s1); }
        else      { dst[0] = s0; dst[16] = s1; }
      }
    }
  }
}

// ---------------- epilogue: out[g][c] /= denom[g][c/16]; empty graphs -> 0 ----------------
__global__ void k_div(float* __restrict__ out, const float* __restrict__ denom) {
  int i = blockIdx.x * 256 + threadIdx.x;
  if (i >= NG * GDIM / 4) return;
  float d = denom[(size_t)(i >> 6) * NH + ((i & 63) >> 2)];
  float r = d > 0.f ? 1.0f / d : 0.f;
  float4 v = ((float4*)out)[i];
  v.x *= r; v.y *= r; v.z *= r; v.w *= r;
  ((float4*)out)[i] = v;
}

extern "C" void kernel_launch(void* const* d_in, const int* in_sizes, int n_in,
                              void* d_out, int out_size, void* d_ws, size_t ws_size,
                              hipStream_t stream) {
  (void)in_sizes; (void)n_in; (void)out_size; (void)ws_size;
  const float* X  = (const float*)d_in[0];
  const int* seg  = (const int*)d_in[1];
  const float* s1 = (const float*)d_in[3];
  const float* s2 = (const float*)d_in[4];
  const float* t1 = (const float*)d_in[5];
  const float* t2 = (const float*)d_in[6];
  float* out = (float*)d_out;
  char* ws = (char*)d_ws;

  unsigned short* WB = (unsigned short*)ws;
  float* denom = (float*)(ws + (1 << 19));

  k_prep<<<392, 256, 0, stream>>>(s1, s2, t1, t2, WB);
  k_zero<<<13282, 256, 0, stream>>>(out, denom);
  k_main<<<NBLK, 512, 0, stream>>>(X, WB, WB + 32768, WB + 98304, WB + 65536,
                                   seg, denom, out);
  k_div<<<12500, 256, 0, stream>>>(out, denom);
}